// Round 16
// baseline (53.785 us; speedup 1.0000x reference)
//
#include <hip/hip_runtime.h>
#include <math.h>

namespace {
constexpr int B_ = 32, C_ = 256, H_ = 32, W_ = 128, A_ = 64;
constexpr int AA = A_ * A_;       // 4096 positions per batch
constexpr int HW = H_ * W_;       // 4096 floats per (b,c) image = 16 KB
constexpr int CPB = 16;           // channels per block -> 512 blocks = 2/CU fill
constexpr int TPB = 1024;         // threads per block (16 waves)
constexpr float MPP = 1.6f;       // 0.2 * 512 / 64
constexpr float PI_F = 3.14159265358979323846f;
typedef float vf4 __attribute__((ext_vector_type(4)));   // native vec for NT store
}

struct Pmat {
    float p00, p01, p02, p03;
    float p10, p11, p12, p13;
    float p20, p21, p22, p23;
};

__device__ __forceinline__ Pmat make_P(int b,
                                       const float* __restrict__ shift_u,
                                       const float* __restrict__ shift_v,
                                       const float* __restrict__ heading,
                                       const float* __restrict__ camk) {
    float su = 20.f * shift_u[b];
    float sv = 20.f * shift_v[b];
    float h  = heading[b] * (10.f / 180.f) * PI_F;
    float ch = cosf(h);
    float sh = -sinf(h);   // sin(-h)

    const float* K = camk + b * 9;
    float k00 = K[0] * 0.125f, k01 = K[1] * 0.125f, k02 = K[2] * 0.125f;
    float k10 = K[3] * 0.125f, k11 = K[4] * 0.125f, k12 = K[5] * 0.125f;
    float k20 = K[6],          k21 = K[7],          k22 = K[8];

    Pmat P;
    P.p00 = k00 * ch + k02 * sh;  P.p01 = k01;
    P.p02 = -k00 * sh + k02 * ch; P.p03 = k00 * sv + k01 * 1.65f - k02 * su;
    P.p10 = k10 * ch + k12 * sh;  P.p11 = k11;
    P.p12 = -k10 * sh + k12 * ch; P.p13 = k10 * sv + k11 * 1.65f - k12 * su;
    P.p20 = k20 * ch + k22 * sh;  P.p21 = k21;
    P.p22 = -k20 * sh + k22 * ch; P.p23 = k20 * sv + k21 * 1.65f - k22 * su;
    return P;
}

__device__ __forceinline__ float4 uv_at(const Pmat& P, int pos, float Y) {
    int i = pos >> 6, j = pos & 63;
    float X = MPP * (float)(i - 32);
    float Z = MPP * (float)(j - 32);

    float u1 = P.p00 * X + P.p02 * Z + P.p03;
    float v1 = P.p10 * X + P.p12 * Z + P.p13;
    float w1 = P.p20 * X + P.p22 * Z + P.p23;

    float d0 = fmaxf(w1, 1e-6f);
    float u0 = u1 / d0, v0 = v1 / d0;

    float u1h = u1 + P.p01 * Y;
    float v1h = v1 + P.p11 * Y;
    float w1h = w1 + P.p21 * Y;
    float dh = fmaxf(w1h, 1e-6f);
    float uh = u1h / dh, vh = v1h / dh;

    return make_float4(u0, v0, uh, vh);
}

// Weights premultiplied by valid; LDS dword index, unclamped +1/+128/+129 taps
// (linear pitch 128 — r15 showed padding INCREASES conflicts here).
// Edge overflow taps carry weight exactly 0; they read the adjacent buffer /
// zero tail, which is guaranteed finite (never NaN/inf from uninit).
__device__ __forceinline__ void mk(float ix, float iy, float4& w, int& ad) {
    bool valid = (ix >= 0.f) && (ix <= (float)(W_ - 1)) &&
                 (iy >= 0.f) && (iy <= (float)(H_ - 1));
    float x0f = floorf(ix), y0f = floorf(iy);
    float fx = ix - x0f, fy = iy - y0f;
    float xa = fminf(fmaxf(x0f, 0.f), 127.f);
    float ya = fminf(fmaxf(y0f, 0.f), 31.f);
    int a = (int)fmaf(ya, 128.f, xa);
    float gx = 1.f - fx, gy = 1.f - fy;
    w = valid ? make_float4(gx * gy, fx * gy, gx * fy, fx * fy)
              : make_float4(0.f, 0.f, 0.f, 0.f);
    ad = valid ? a : 0;
}

__device__ __forceinline__ float tap4(const float* __restrict__ im, int ad, float4 w) {
    const float* t = im + ad;
    return fmaf(w.x, t[0], fmaf(w.y, t[1], fmaf(w.z, t[128], w.w * t[129])));
}

// r14 structure with HALF the barriers: 2 channels per rendezvous, 4-buffer
// LDS rotation. Pair p uses buffers {0,1} or {2,3} (alternating); writer of
// a buffer at pair p+2 is behind barrier p+1, readers at pair p drained
// their LDS reads (own lgkmcnt(0)) before entering barrier p+1 -> safe.
// Per pair: {ds_write 2 staged images -> issue next 2 image + 2 sat loads
// (stay in flight across the barrier) -> lgkm-only barrier -> compute 2
// channels + 2 NT stores}.
__global__ __launch_bounds__(TPB) void proj_kernel(
        const float* __restrict__ grd,
        const float* __restrict__ sat,
        float* __restrict__ out,
        const float* __restrict__ ph,
        const float* __restrict__ shift_u,
        const float* __restrict__ shift_v,
        const float* __restrict__ heading,
        const float* __restrict__ camk) {
    __shared__ float img[4 * HW + 132];
    int cg = blockIdx.x, b = blockIdx.y;
    int c0 = cg * CPB;
    int tid = threadIdx.x;
    int p0 = tid * 4;
    int bbase = b << 12;

    const float* gbase = grd + ((size_t)b * C_ + c0) * HW;
    const float* satbase = sat + (size_t)c0 * AA + p0;
    float* outbase = out + ((size_t)b * C_ + c0) * AA + p0;

    // prologue: issue channel 0,1 image loads + their sat rows
    float4 imA = ((const float4*)gbase)[tid];
    float4 imB = ((const float4*)(gbase + HW))[tid];
    float4 svA = *(const float4*)(satbase);
    float4 svB = *(const float4*)(satbase + (size_t)AA);

    // zero-init: head of buffers 1,2,3 is covered by the previous buffer's
    // data (overflow taps weight-0 read into the next buffer's first row,
    // finite after first staging) — but on the FIRST pair buffers 1's head
    // is staged same-iteration, fine; only the tail after buffer 3 needs
    // permanent zeros, plus buffer 1..3 are fully staged before any read of
    // them. Tail after buf3:
    if (tid < 33)
        ((float4*)(img + 4 * HW))[tid] = make_float4(0.f, 0.f, 0.f, 0.f);

    // per-position sampling descriptors, computed once for all 16 channels
    float4 w[4][2];
    int ad[4][2];
    {
        Pmat P = make_P(b, shift_u, shift_v, heading, camk);
        const float* phb = ph + bbase;
#pragma unroll
        for (int k = 0; k < 4; ++k) {
            float4 q = uv_at(P, p0 + k, -phb[p0 + k]);
            mk(q.x, q.y, w[k][0], ad[k][0]);
            mk(q.z, q.w, w[k][1], ad[k][1]);
        }
    }

#pragma unroll
    for (int pr = 0; pr < CPB / 2; ++pr) {
        const int base = (pr & 1) * 2 * HW;   // buffers {0,1} or {2,3}
        const int ch = pr * 2;
        // stage both channels of the pair (regs -> LDS)
        *(float4*)(img + base + p0) = imA;
        *(float4*)(img + base + HW + p0) = imB;

        // issue next pair's loads (stay in flight across the barrier)
        float4 nimA, nimB, nsvA, nsvB;
        if (ch + 2 < CPB) {
            nimA = ((const float4*)(gbase + (size_t)(ch + 2) * HW))[tid];
            nimB = ((const float4*)(gbase + (size_t)(ch + 3) * HW))[tid];
            nsvA = *(const float4*)(satbase + (size_t)(ch + 2) * AA);
            nsvB = *(const float4*)(satbase + (size_t)(ch + 3) * AA);
        }

        // barrier with LDS-only drain: vmem prefetches stay in flight
        asm volatile("s_waitcnt lgkmcnt(0)" ::: "memory");
        __builtin_amdgcn_s_barrier();

        // compute channel ch (buffer base) and ch+1 (buffer base+HW)
#pragma unroll
        for (int half = 0; half < 2; ++half) {
            const float* im = img + base + half * HW;
            float4 sv = half ? svB : svA;
            float r[4];
#pragma unroll
            for (int k = 0; k < 4; ++k) {
                float g0 = tap4(im, ad[k][0], w[k][0]);
                float gh = tap4(im, ad[k][1], w[k][1]);
                float s = (k == 0) ? sv.x : (k == 1) ? sv.y
                        : (k == 2) ? sv.z : sv.w;
                r[k] = fmaf(s, gh - g0, g0);
            }
            vf4 rv = {r[0], r[1], r[2], r[3]};
            __builtin_nontemporal_store(
                rv, (vf4*)(outbase + (size_t)(ch + half) * AA));
        }
        imA = nimA; imB = nimB; svA = nsvA; svB = nsvB;
    }
}

extern "C" void kernel_launch(void* const* d_in, const int* in_sizes, int n_in,
                              void* d_out, int out_size, void* d_ws, size_t ws_size,
                              hipStream_t stream) {
    (void)in_sizes; (void)n_in; (void)out_size; (void)d_ws; (void)ws_size;
    const float* grd  = (const float*)d_in[0];   // [B,C,H,W]
    const float* ph   = (const float*)d_in[1];   // [B,1,A,A]
    const float* s_u  = (const float*)d_in[2];   // [B,1]
    const float* s_v  = (const float*)d_in[3];   // [B,1]
    const float* hd   = (const float*)d_in[4];   // [B,1]
    const float* ck   = (const float*)d_in[5];   // [B,3,3]
    const float* sat  = (const float*)d_in[6];   // [1,C,A,A]
    float* out = (float*)d_out;

    proj_kernel<<<dim3(C_ / CPB, B_), TPB, 0, stream>>>(
        grd, sat, out, ph, s_u, s_v, hd, ck);
}

// Round 17
// 51.661 us; speedup vs baseline: 1.0411x; 1.0411x over previous
//
#include <hip/hip_runtime.h>
#include <math.h>

namespace {
constexpr int B_ = 32, C_ = 256, H_ = 32, W_ = 128, A_ = 64;
constexpr int AA = A_ * A_;       // 4096 positions per batch
constexpr int HW = H_ * W_;       // 4096 floats per (b,c) image = 16 KB
constexpr int CPB = 16;           // channels per block -> 512 blocks = 2/CU fill
constexpr int TPB = 1024;         // threads per block (16 waves)
constexpr float MPP = 1.6f;       // 0.2 * 512 / 64
constexpr float PI_F = 3.14159265358979323846f;
typedef float vf4 __attribute__((ext_vector_type(4)));   // native vec for NT store
}

#define SB() __builtin_amdgcn_sched_barrier(0)

struct Pmat {
    float p00, p01, p02, p03;
    float p10, p11, p12, p13;
    float p20, p21, p22, p23;
};

__device__ __forceinline__ Pmat make_P(int b,
                                       const float* __restrict__ shift_u,
                                       const float* __restrict__ shift_v,
                                       const float* __restrict__ heading,
                                       const float* __restrict__ camk) {
    float su = 20.f * shift_u[b];
    float sv = 20.f * shift_v[b];
    float h  = heading[b] * (10.f / 180.f) * PI_F;
    float ch = cosf(h);
    float sh = -sinf(h);   // sin(-h)

    const float* K = camk + b * 9;
    float k00 = K[0] * 0.125f, k01 = K[1] * 0.125f, k02 = K[2] * 0.125f;
    float k10 = K[3] * 0.125f, k11 = K[4] * 0.125f, k12 = K[5] * 0.125f;
    float k20 = K[6],          k21 = K[7],          k22 = K[8];

    Pmat P;
    P.p00 = k00 * ch + k02 * sh;  P.p01 = k01;
    P.p02 = -k00 * sh + k02 * ch; P.p03 = k00 * sv + k01 * 1.65f - k02 * su;
    P.p10 = k10 * ch + k12 * sh;  P.p11 = k11;
    P.p12 = -k10 * sh + k12 * ch; P.p13 = k10 * sv + k11 * 1.65f - k12 * su;
    P.p20 = k20 * ch + k22 * sh;  P.p21 = k21;
    P.p22 = -k20 * sh + k22 * ch; P.p23 = k20 * sv + k21 * 1.65f - k22 * su;
    return P;
}

__device__ __forceinline__ float4 uv_at(const Pmat& P, int pos, float Y) {
    int i = pos >> 6, j = pos & 63;
    float X = MPP * (float)(i - 32);
    float Z = MPP * (float)(j - 32);

    float u1 = P.p00 * X + P.p02 * Z + P.p03;
    float v1 = P.p10 * X + P.p12 * Z + P.p13;
    float w1 = P.p20 * X + P.p22 * Z + P.p23;

    float d0 = fmaxf(w1, 1e-6f);
    float u0 = u1 / d0, v0 = v1 / d0;

    float u1h = u1 + P.p01 * Y;
    float v1h = v1 + P.p11 * Y;
    float w1h = w1 + P.p21 * Y;
    float dh = fmaxf(w1h, 1e-6f);
    float uh = u1h / dh, vh = v1h / dh;

    return make_float4(u0, v0, uh, vh);
}

// Weights premultiplied by valid; LDS dword index, unclamped +1/+128/+129 taps
// (linear pitch — r15 showed padding INCREASES conflicts for this access).
// Edge overflow taps carry weight exactly 0; they read the next buffer's head
// (staged or zero-inited, always finite) or the permanent zero tail.
__device__ __forceinline__ void mk(float ix, float iy, float4& w, int& ad) {
    bool valid = (ix >= 0.f) && (ix <= (float)(W_ - 1)) &&
                 (iy >= 0.f) && (iy <= (float)(H_ - 1));
    float x0f = floorf(ix), y0f = floorf(iy);
    float fx = ix - x0f, fy = iy - y0f;
    float xa = fminf(fmaxf(x0f, 0.f), 127.f);
    float ya = fminf(fmaxf(y0f, 0.f), 31.f);
    int a = (int)fmaf(ya, 128.f, xa);
    float gx = 1.f - fx, gy = 1.f - fy;
    w = valid ? make_float4(gx * gy, fx * gy, gx * fy, fx * fy)
              : make_float4(0.f, 0.f, 0.f, 0.f);
    ad = valid ? a : 0;
}

__device__ __forceinline__ float tap4(const float* __restrict__ im, int ad, float4 w) {
    const float* t = im + ad;
    return fmaf(w.x, t[0], fmaf(w.y, t[1], fmaf(w.z, t[128], w.w * t[129])));
}

// direct global->LDS DMA, 16B per lane, dest = wave-uniform base + lane*16
__device__ __forceinline__ void gll16(const float* g, float* l) {
    __builtin_amdgcn_global_load_lds(
        (const __attribute__((address_space(1))) void*)g,
        (__attribute__((address_space(3))) void*)l, 16, 0, 0);
}

__device__ __forceinline__ void vmwait(int n) {
    if (n == 6)      asm volatile("s_waitcnt vmcnt(6)" ::: "memory");
    else if (n == 5) asm volatile("s_waitcnt vmcnt(5)" ::: "memory");
    else if (n == 4) asm volatile("s_waitcnt vmcnt(4)" ::: "memory");
    else if (n == 2) asm volatile("s_waitcnt vmcnt(2)" ::: "memory");
    else             asm volatile("s_waitcnt vmcnt(0)" ::: "memory");
}

// r14 structure with global_load_lds staging + counted-vmcnt 2-deep pipeline.
// 4-buffer LDS rotation (buf k&3). Per channel k:
//   [issue DMA(k+2 -> buf (k+2)&3) + sat(k+2) reg load]  <- SB-fenced block
//   vmcnt(N_k): retires DMA k / sat k, leaves k+1,k+2 IN FLIGHT
//   s_barrier; compute from buf k&3; NT store.
// Laggard safety: DMA re-targeting buf j only issues after a barrier all
// readers of j have passed. N_k counted from SB-pinned issue order
// (prologue block=4 ops, per-iter block=2 ops, 1 NT store per iter).
__global__ __launch_bounds__(TPB) void proj_kernel(
        const float* __restrict__ grd,
        const float* __restrict__ sat,
        float* __restrict__ out,
        const float* __restrict__ ph,
        const float* __restrict__ shift_u,
        const float* __restrict__ shift_v,
        const float* __restrict__ heading,
        const float* __restrict__ camk) {
    __shared__ float img[4 * HW + 132];
    int cg = blockIdx.x, b = blockIdx.y;
    int c0 = cg * CPB;
    int tid = threadIdx.x;
    int p0 = tid * 4;
    int bbase = b << 12;
    const int wb = (tid >> 6) << 8;   // wave-uniform LDS base (floats)

    const float* gbase = grd + ((size_t)b * C_ + c0) * HW;
    const float* satbase = sat + (size_t)c0 * AA + p0;
    float* outbase = out + ((size_t)b * C_ + c0) * AA + p0;

    // per-position sampling descriptors FIRST (ph consumed here; any plain
    // load consumed pre-loop would drain vmcnt, so no DMAs are in flight yet)
    float4 w[4][2];
    int ad[4][2];
    {
        Pmat P = make_P(b, shift_u, shift_v, heading, camk);
        const float* phb = ph + bbase;
#pragma unroll
        for (int k = 0; k < 4; ++k) {
            float4 q = uv_at(P, p0 + k, -phb[p0 + k]);
            mk(q.x, q.y, w[k][0], ad[k][0]);
            mk(q.z, q.w, w[k][1], ad[k][1]);
        }
    }

    // zero-init heads of buf1..3 + permanent tail (132 floats each): overflow
    // taps may read these mid-DMA on early iters; must be finite. Drain LDS
    // writes BEFORE issuing DMAs so zeros can't land on top of DMA data.
    if (tid < 132) {
        int r = tid / 33, o = (tid % 33) * 4;
        *(float4*)(img + (r + 1) * HW + o) = make_float4(0.f, 0.f, 0.f, 0.f);
    }
    asm volatile("s_waitcnt lgkmcnt(0)" ::: "memory");
    __builtin_amdgcn_s_barrier();   // zeros visible to all waves

    float4 svq[3];

    // prologue issue block P = {G0, S0, G1, S1}
    SB();
    gll16(gbase + (size_t)0 * HW + p0, img + 0 * HW + wb);
    svq[0] = *(const float4*)(satbase);
    gll16(gbase + (size_t)1 * HW + p0, img + 1 * HW + wb);
    svq[1] = *(const float4*)(satbase + (size_t)AA);
    SB();

#pragma unroll
    for (int k = 0; k < CPB; ++k) {
        // issue block I_k = {G_{k+2}, S_{k+2}}
        if (k + 2 < CPB) {
            gll16(gbase + (size_t)(k + 2) * HW + p0,
                  img + ((k + 2) & 3) * HW + wb);
            svq[(k + 2) % 3] = *(const float4*)(satbase + (size_t)(k + 2) * AA);
        }
        SB();
        // counted wait: retire through the block containing {G_k, S_k}.
        // k=0: after P -> I_0(2). k=1: after P -> I_0(2)+T0+I_1(2)=5.
        // 2<=k<=13: after I_{k-2} -> T_{k-2}+I_{k-1}(2)+T_{k-1}+I_k(2)=6.
        // k=14: T12+I_13(2)+T13=4.  k=15: T13+T14=2.
        vmwait(k == 0 ? 2 : k == 1 ? 5 : k <= 13 ? 6 : k == 14 ? 4 : 2);
        __builtin_amdgcn_s_barrier();
        SB();

        const float* im = img + (k & 3) * HW;
        float4 sv = svq[k % 3];
        float r[4];
#pragma unroll
        for (int kk = 0; kk < 4; ++kk) {
            float g0 = tap4(im, ad[kk][0], w[kk][0]);
            float gh = tap4(im, ad[kk][1], w[kk][1]);
            float s = (kk == 0) ? sv.x : (kk == 1) ? sv.y
                    : (kk == 2) ? sv.z : sv.w;
            r[kk] = fmaf(s, gh - g0, g0);
        }
        vf4 rv = {r[0], r[1], r[2], r[3]};
        __builtin_nontemporal_store(rv, (vf4*)(outbase + (size_t)k * AA));
        SB();
    }
}

extern "C" void kernel_launch(void* const* d_in, const int* in_sizes, int n_in,
                              void* d_out, int out_size, void* d_ws, size_t ws_size,
                              hipStream_t stream) {
    (void)in_sizes; (void)n_in; (void)out_size; (void)d_ws; (void)ws_size;
    const float* grd  = (const float*)d_in[0];   // [B,C,H,W]
    const float* ph   = (const float*)d_in[1];   // [B,1,A,A]
    const float* s_u  = (const float*)d_in[2];   // [B,1]
    const float* s_v  = (const float*)d_in[3];   // [B,1]
    const float* hd   = (const float*)d_in[4];   // [B,1]
    const float* ck   = (const float*)d_in[5];   // [B,3,3]
    const float* sat  = (const float*)d_in[6];   // [1,C,A,A]
    float* out = (float*)d_out;

    proj_kernel<<<dim3(C_ / CPB, B_), TPB, 0, stream>>>(
        grd, sat, out, ph, s_u, s_v, hd, ck);
}

// Round 18
// 47.461 us; speedup vs baseline: 1.1332x; 1.0885x over previous
//
#include <hip/hip_runtime.h>
#include <math.h>

namespace {
constexpr int B_ = 32, C_ = 256, H_ = 32, W_ = 128, A_ = 64;
constexpr int AA = A_ * A_;       // 4096 positions per batch
constexpr int HW = H_ * W_;       // 4096 floats per (b,c) image = 16 KB
constexpr int CPB = 16;           // channels per block -> 512 blocks = 2/CU fill
constexpr int TPB = 1024;         // threads per block (16 waves)
constexpr float MPP = 1.6f;       // 0.2 * 512 / 64
constexpr float PI_F = 3.14159265358979323846f;
typedef float vf4 __attribute__((ext_vector_type(4)));   // native vec for NT store
}

struct Pmat {
    float p00, p01, p02, p03;
    float p10, p11, p12, p13;
    float p20, p21, p22, p23;
};

__device__ __forceinline__ Pmat make_P(int b,
                                       const float* __restrict__ shift_u,
                                       const float* __restrict__ shift_v,
                                       const float* __restrict__ heading,
                                       const float* __restrict__ camk) {
    float su = 20.f * shift_u[b];
    float sv = 20.f * shift_v[b];
    float h  = heading[b] * (10.f / 180.f) * PI_F;
    float ch = cosf(h);
    float sh = -sinf(h);   // sin(-h)

    const float* K = camk + b * 9;
    float k00 = K[0] * 0.125f, k01 = K[1] * 0.125f, k02 = K[2] * 0.125f;
    float k10 = K[3] * 0.125f, k11 = K[4] * 0.125f, k12 = K[5] * 0.125f;
    float k20 = K[6],          k21 = K[7],          k22 = K[8];

    Pmat P;
    P.p00 = k00 * ch + k02 * sh;  P.p01 = k01;
    P.p02 = -k00 * sh + k02 * ch; P.p03 = k00 * sv + k01 * 1.65f - k02 * su;
    P.p10 = k10 * ch + k12 * sh;  P.p11 = k11;
    P.p12 = -k10 * sh + k12 * ch; P.p13 = k10 * sv + k11 * 1.65f - k12 * su;
    P.p20 = k20 * ch + k22 * sh;  P.p21 = k21;
    P.p22 = -k20 * sh + k22 * ch; P.p23 = k20 * sv + k21 * 1.65f - k22 * su;
    return P;
}

__device__ __forceinline__ float4 uv_at(const Pmat& P, int pos, float Y) {
    int i = pos >> 6, j = pos & 63;
    float X = MPP * (float)(i - 32);
    float Z = MPP * (float)(j - 32);

    float u1 = P.p00 * X + P.p02 * Z + P.p03;
    float v1 = P.p10 * X + P.p12 * Z + P.p13;
    float w1 = P.p20 * X + P.p22 * Z + P.p23;

    float d0 = fmaxf(w1, 1e-6f);
    float u0 = u1 / d0, v0 = v1 / d0;

    float u1h = u1 + P.p01 * Y;
    float v1h = v1 + P.p11 * Y;
    float w1h = w1 + P.p21 * Y;
    float dh = fmaxf(w1h, 1e-6f);
    float uh = u1h / dh, vh = v1h / dh;

    return make_float4(u0, v0, uh, vh);
}

// Weights premultiplied by valid; LDS dword index, unclamped +1/+128/+129 taps.
// Edge overflow taps carry weight exactly 0; they read the other buffer /
// zero tail, which is guaranteed finite (never NaN/inf from uninit).
__device__ __forceinline__ void mk(float ix, float iy, float4& w, int& ad) {
    bool valid = (ix >= 0.f) && (ix <= (float)(W_ - 1)) &&
                 (iy >= 0.f) && (iy <= (float)(H_ - 1));
    float x0f = floorf(ix), y0f = floorf(iy);
    float fx = ix - x0f, fy = iy - y0f;
    float xa = fminf(fmaxf(x0f, 0.f), 127.f);
    float ya = fminf(fmaxf(y0f, 0.f), 31.f);
    int a = (int)fmaf(ya, 128.f, xa);
    float gx = 1.f - fx, gy = 1.f - fy;
    w = valid ? make_float4(gx * gy, fx * gy, gx * fy, fx * fy)
              : make_float4(0.f, 0.f, 0.f, 0.f);
    ad = valid ? a : 0;
}

__device__ __forceinline__ float tap4(const float* __restrict__ im, int ad, float4 w) {
    const float* t = im + ad;
    return fmaf(w.x, t[0], fmaf(w.y, t[1], fmaf(w.z, t[128], w.w * t[129])));
}

// SINGLE fused kernel (r14 winner, final): one block per (b, 16-channel
// group) -> 512 blocks x 16 waves = 2 blocks/CU. Descriptors (make_P +
// uv_at + mk) computed ONCE per thread inline, reused for all 16 channels.
// Per channel: {ds_write staged image -> reg-prefetch next -> lgkmcnt-only
// barrier (prefetch stays in flight) -> compute + NT store}.
// Falsified alternatives: pitch-132 padding (conflicts UP, r15), 2-ch/barrier
// 4-buf rotation (slower, r16), global_load_lds + counted vmcnt (slower, r17),
// launch_bounds min-wave pin (spills, r10), pos-split z-grid (HBM dup, r12).
__global__ __launch_bounds__(TPB) void proj_kernel(
        const float* __restrict__ grd,
        const float* __restrict__ sat,
        float* __restrict__ out,
        const float* __restrict__ ph,
        const float* __restrict__ shift_u,
        const float* __restrict__ shift_v,
        const float* __restrict__ heading,
        const float* __restrict__ camk) {
    __shared__ float img[2 * HW + 132];
    int cg = blockIdx.x, b = blockIdx.y;
    int c0 = cg * CPB;
    int tid = threadIdx.x;
    int p0 = tid * 4;
    int bbase = b << 12;

    const float* gbase = grd + ((size_t)b * C_ + c0) * HW;

    // prologue: issue load of channel 0 image (1 float4/thread)
    float4 streg = ((const float4*)gbase)[tid];

    // zero-init buf1 head + permanent tail (overflow-tap safety on iter 0)
    if (tid < 33) {
        ((float4*)(img + HW))[tid] = make_float4(0.f, 0.f, 0.f, 0.f);
        ((float4*)(img + 2 * HW))[tid] = make_float4(0.f, 0.f, 0.f, 0.f);
    }

    // per-position sampling descriptors, computed once for all 16 channels
    float4 w[4][2];
    int ad[4][2];
    {
        Pmat P = make_P(b, shift_u, shift_v, heading, camk);
        const float* phb = ph + bbase;
#pragma unroll
        for (int k = 0; k < 4; ++k) {
            float4 q = uv_at(P, p0 + k, -phb[p0 + k]);
            mk(q.x, q.y, w[k][0], ad[k][0]);
            mk(q.z, q.w, w[k][1], ad[k][1]);
        }
    }

    float* outbase = out + ((size_t)b * C_ + c0) * AA + p0;
    const float* satbase = sat + (size_t)c0 * AA + p0;

#pragma unroll
    for (int cp = 0; cp < CPB; ++cp) {
        int bufo = (cp & 1) * HW;
        // stage current channel (regs -> LDS)
        *(float4*)(img + bufo + p0) = streg;
        // prefetch next channel (stays in flight across the barrier)
        float4 nxt;
        if (cp + 1 < CPB)
            nxt = ((const float4*)(gbase + (size_t)(cp + 1) * HW))[tid];
        float4 sv = *(const float4*)(satbase + (size_t)cp * AA);
        // barrier with LDS-only drain: do NOT wait vmcnt (prefetch in flight)
        asm volatile("s_waitcnt lgkmcnt(0)" ::: "memory");
        __builtin_amdgcn_s_barrier();

        const float* im = img + bufo;
        float r[4];
#pragma unroll
        for (int k = 0; k < 4; ++k) {
            float g0 = tap4(im, ad[k][0], w[k][0]);
            float gh = tap4(im, ad[k][1], w[k][1]);
            float s = (k == 0) ? sv.x : (k == 1) ? sv.y : (k == 2) ? sv.z : sv.w;
            r[k] = fmaf(s, gh - g0, g0);
        }
        vf4 rv = {r[0], r[1], r[2], r[3]};
        __builtin_nontemporal_store(rv, (vf4*)(outbase + (size_t)cp * AA));
        streg = nxt;
        // Laggard-safety: a wave's reads of buffer X (iter cp) are drained by
        // its own lgkmcnt(0) before barrier cp+1; writers of X (iter cp+2)
        // write only after barrier cp+1 -> no read/write race.
    }
}

extern "C" void kernel_launch(void* const* d_in, const int* in_sizes, int n_in,
                              void* d_out, int out_size, void* d_ws, size_t ws_size,
                              hipStream_t stream) {
    (void)in_sizes; (void)n_in; (void)out_size; (void)d_ws; (void)ws_size;
    const float* grd  = (const float*)d_in[0];   // [B,C,H,W]
    const float* ph   = (const float*)d_in[1];   // [B,1,A,A]
    const float* s_u  = (const float*)d_in[2];   // [B,1]
    const float* s_v  = (const float*)d_in[3];   // [B,1]
    const float* hd   = (const float*)d_in[4];   // [B,1]
    const float* ck   = (const float*)d_in[5];   // [B,3,3]
    const float* sat  = (const float*)d_in[6];   // [1,C,A,A]
    float* out = (float*)d_out;

    proj_kernel<<<dim3(C_ / CPB, B_), TPB, 0, stream>>>(
        grd, sat, out, ph, s_u, s_v, hd, ck);
}